// Round 6
// baseline (507.813 us; speedup 1.0000x reference)
//
#include <hip/hip_runtime.h>
#include <math.h>

typedef __attribute__((ext_vector_type(8))) short short8;
typedef __attribute__((ext_vector_type(4))) float f32x4;
typedef unsigned short ushort_t;

#define KVIN 15360   // 15069 padded to multiple of 32*16 splits (960*16)

__device__ __forceinline__ ushort_t f2bf(float f) {
  unsigned u = __float_as_uint(f);
  return (ushort_t)((u + 0x7fffu + ((u >> 16) & 1u)) >> 16);  // RNE
}
__device__ __forceinline__ float bf2f(ushort_t h) {
  return __uint_as_float(((unsigned)h) << 16);
}

// ---------------- block reduction helpers (256-thread blocks) ----------------
__device__ __forceinline__ float blockReduceSum256(float v, float* red) {
  #pragma unroll
  for (int o = 32; o; o >>= 1) v += __shfl_xor(v, o);
  int wid = threadIdx.x >> 6, lane = threadIdx.x & 63;
  if (lane == 0) red[wid] = v;
  __syncthreads();
  v = red[0] + red[1] + red[2] + red[3];
  __syncthreads();
  return v;
}
__device__ __forceinline__ float blockReduceMax256(float v, float* red) {
  #pragma unroll
  for (int o = 32; o; o >>= 1) v = fmaxf(v, __shfl_xor(v, o));
  int wid = threadIdx.x >> 6, lane = threadIdx.x & 63;
  if (lane == 0) red[wid] = v;
  __syncthreads();
  v = fmaxf(fmaxf(red[0], red[1]), fmaxf(red[2], red[3]));
  __syncthreads();
  return v;
}

// ============ 1-pass bf16 MFMA GEMM, 128x128 tile, conflict-free LDS ============
// C = A @ B^T (+bias). A: bf16 hi plane. B: bf16 (BF16B) or fp32 (converted in staging).
// M = 512 exact (grid.y=4). N ragged (guarded). K%32==0; kChunk%32==0 (split-K via z).
// aZ/bZ/cZ: per-z element offsets (head batching / split-K partials).
// LDS layout: 16B unit (row,q) at unit-idx (row>>4)*64 + q*16 + (row&15).
//   -> frag read addr = base + 16*lane (conflict-free); stager thread t writes
//      units {t, t+256} at bytes {16t, 16t+4096} (conflict-free).
template <bool BF16B, bool BIAS, bool CAUSAL, bool POUT>
__global__ __launch_bounds__(256, 2) void glds(
    const ushort_t* __restrict__ A, const void* __restrict__ Bv,
    const float* __restrict__ bias, float* __restrict__ C, ushort_t* __restrict__ Ch,
    int N, int K, int lda, int ldb, int ldc,
    int kChunk, long aZ, long bZ, long cZ)
{
  const int m0 = blockIdx.y * 128, n0 = blockIdx.x * 128;
  if (CAUSAL && n0 > m0 + 127) return;   // tile fully above diagonal
  __shared__ ushort_t sA[4096], sB[4096];   // 512 units x 8 bf16 each
  const int tid = threadIdx.x, z = blockIdx.z;
  const int kBeg = kChunk ? z * kChunk : 0;
  const int kEnd = kChunk ? kBeg + kChunk : K;
  A += (size_t)z * aZ;
  const ushort_t* Bh = (const ushort_t*)Bv;
  const float*    Bf = (const float*)Bv;
  if (BF16B) Bh += (size_t)z * bZ; else Bf += (size_t)z * bZ;
  C += (size_t)z * cZ;
  if (POUT) Ch += (size_t)z * cZ;

  // staging: thread t handles units t (rows 0-63 region) and t+256 (rows 64-127)
  const int r0 = ((tid >> 6) << 4) | (tid & 15);   // unit t -> row
  const int q0 = (tid >> 4) & 3;                   // k-chunk within 32
  const int r1 = r0 + 64;                          // unit t+256 -> row
  const ushort_t* pA0 = A + (size_t)(m0 + r0) * lda + (q0 << 3);
  const ushort_t* pA1 = A + (size_t)(m0 + r1) * lda + (q0 << 3);
  const int gn0 = n0 + r0, gn1 = n0 + r1;
  const bool bok0 = gn0 < N, bok1 = gn1 < N;
  const ushort_t* pB0h = Bh + (size_t)gn0 * ldb + (q0 << 3);
  const ushort_t* pB1h = Bh + (size_t)gn1 * ldb + (q0 << 3);
  const float*    pB0f = Bf + (size_t)gn0 * ldb + (q0 << 3);
  const float*    pB1f = Bf + (size_t)gn1 * ldb + (q0 << 3);

  // waves 2x2, each 64x64
  const int lane = tid & 63;
  const int wrb = (tid >> 7) & 1;   // row-block: rows wrb*64..+63
  const int wcb = (tid >> 6) & 1;   // col-block
  const int fr = lane & 15, fq = lane >> 4;

  f32x4 acc[4][4] = {};
  const short8 z8 = {0, 0, 0, 0, 0, 0, 0, 0};
  const float4 z4 = make_float4(0.f, 0.f, 0.f, 0.f);
  short8 ra0, ra1, rb0, rb1;
  float4 f00, f01, f10, f11;

  // preload first k-step
  ra0 = *(const short8*)(pA0 + kBeg);
  ra1 = *(const short8*)(pA1 + kBeg);
  if (BF16B) {
    rb0 = bok0 ? *(const short8*)(pB0h + kBeg) : z8;
    rb1 = bok1 ? *(const short8*)(pB1h + kBeg) : z8;
  } else {
    f00 = bok0 ? *(const float4*)(pB0f + kBeg) : z4;
    f01 = bok0 ? *(const float4*)(pB0f + kBeg + 4) : z4;
    f10 = bok1 ? *(const float4*)(pB1f + kBeg) : z4;
    f11 = bok1 ? *(const float4*)(pB1f + kBeg + 4) : z4;
  }

  for (int k0 = kBeg; k0 < kEnd; k0 += 32) {
    __syncthreads();  // prior iter's fragment reads complete
    *(short8*)&sA[tid << 3] = ra0;
    *(short8*)&sA[(tid + 256) << 3] = ra1;
    if (BF16B) {
      *(short8*)&sB[tid << 3] = rb0;
      *(short8*)&sB[(tid + 256) << 3] = rb1;
    } else {
      short8 s0, s1;
      #pragma unroll
      for (int j = 0; j < 4; ++j) {
        s0[j] = (short)f2bf(f00[j]); s0[j + 4] = (short)f2bf(f01[j]);
        s1[j] = (short)f2bf(f10[j]); s1[j + 4] = (short)f2bf(f11[j]);
      }
      *(short8*)&sB[tid << 3] = s0;
      *(short8*)&sB[(tid + 256) << 3] = s1;
    }
    if (k0 + 32 < kEnd) {  // prefetch next k-step
      const int k = k0 + 32;
      ra0 = *(const short8*)(pA0 + k);
      ra1 = *(const short8*)(pA1 + k);
      if (BF16B) {
        rb0 = bok0 ? *(const short8*)(pB0h + k) : z8;
        rb1 = bok1 ? *(const short8*)(pB1h + k) : z8;
      } else {
        f00 = bok0 ? *(const float4*)(pB0f + k) : z4;
        f01 = bok0 ? *(const float4*)(pB0f + k + 4) : z4;
        f10 = bok1 ? *(const float4*)(pB1f + k) : z4;
        f11 = bok1 ? *(const float4*)(pB1f + k + 4) : z4;
      }
    }
    __syncthreads();  // writes visible

    short8 fa[4], fb[4];
    #pragma unroll
    for (int f = 0; f < 4; ++f)
      fa[f] = *(const short8*)&sA[((((wrb << 2) + f) << 9) | (lane << 3))];
    #pragma unroll
    for (int g = 0; g < 4; ++g)
      fb[g] = *(const short8*)&sB[((((wcb << 2) + g) << 9) | (lane << 3))];
    #pragma unroll
    for (int f = 0; f < 4; ++f)
      #pragma unroll
      for (int g = 0; g < 4; ++g)
        acc[f][g] = __builtin_amdgcn_mfma_f32_16x16x32_bf16(fa[f], fb[g], acc[f][g], 0, 0, 0);
  }

  // epilogue: C/D layout col=lane&15, row=(lane>>4)*4+reg
  #pragma unroll
  for (int f = 0; f < 4; ++f) {
    const int gm = m0 + (wrb << 6) + f * 16 + fq * 4;
    #pragma unroll
    for (int g = 0; g < 4; ++g) {
      const int gn = n0 + (wcb << 6) + g * 16 + fr;
      if (gn < N) {
        #pragma unroll
        for (int i = 0; i < 4; ++i) {
          float v = acc[f][g][i];
          if (BIAS) v += bias[gn];
          const size_t o = (size_t)(gm + i) * ldc + gn;
          if (POUT) Ch[o] = f2bf(v);
          else      C[o] = v;
        }
      }
    }
  }
}

// ---------------- split-K combine: outh = bf16(sum_z part[z] + bias (+relu)) ----------------
template <bool RELU>
__global__ __launch_bounds__(256) void combine(
    const float* __restrict__ part, const float* __restrict__ bias,
    ushort_t* __restrict__ outh, int nz, long zstride, int total4, int N4)
{
  const int i = blockIdx.x * 256 + threadIdx.x;
  if (i >= total4) return;
  float4 s = ((const float4*)bias)[i % N4];
  for (int z = 0; z < nz; ++z) {
    float4 p = ((const float4*)(part + (size_t)z * zstride))[i];
    s.x += p.x; s.y += p.y; s.z += p.z; s.w += p.w;
  }
  if (RELU) {
    s.x = fmaxf(s.x, 0.f); s.y = fmaxf(s.y, 0.f);
    s.z = fmaxf(s.z, 0.f); s.w = fmaxf(s.w, 0.f);
  }
  ((ushort4*)outh)[i] = make_ushort4(f2bf(s.x), f2bf(s.y), f2bf(s.z), f2bf(s.w));
}

// ---------------- fused split-K combine + residual + LayerNorm ----------------
// x = LN(x + sum_z part[z] + bias) * g + b ; writes x (f32) and xh (bf16 hi)
__global__ __launch_bounds__(256) void ln_parts(
    const float* __restrict__ part, int nz, const float* __restrict__ bias,
    float* __restrict__ x, ushort_t* __restrict__ xh,
    const float* __restrict__ g, const float* __restrict__ b)
{
  const int t = blockIdx.x, tid = threadIdx.x;
  float4 y = ((const float4*)(x + (size_t)t * 1024))[tid];
  float4 s = ((const float4*)bias)[tid];
  for (int z = 0; z < nz; ++z) {
    float4 p = ((const float4*)(part + (size_t)z * 524288 + (size_t)t * 1024))[tid];
    s.x += p.x; s.y += p.y; s.z += p.z; s.w += p.w;
  }
  y.x += s.x; y.y += s.y; y.z += s.z; y.w += s.w;
  __shared__ float red[4];
  float sum = blockReduceSum256(y.x + y.y + y.z + y.w, red);
  const float m = sum * (1.f / 1024.f);
  float dx = y.x - m, dy = y.y - m, dz = y.z - m, dw = y.w - m;
  float q = blockReduceSum256(dx * dx + dy * dy + dz * dz + dw * dw, red);
  const float rs = rsqrtf(q * (1.f / 1024.f) + 1e-5f);
  float4 gg = ((const float4*)g)[tid], bb = ((const float4*)b)[tid];
  float4 o;
  o.x = dx * rs * gg.x + bb.x;
  o.y = dy * rs * gg.y + bb.y;
  o.z = dz * rs * gg.z + bb.z;
  o.w = dw * rs * gg.w + bb.w;
  ((float4*)(x + (size_t)t * 1024))[tid] = o;
  ((ushort4*)xh)[t * 256 + tid] = make_ushort4(f2bf(o.x), f2bf(o.y), f2bf(o.z), f2bf(o.w));
}

// ---------------- fp32 (R x Csrc) -> bf16 hi plane (R x Cdst), zero-padded ----------------
__global__ __launch_bounds__(256) void split_pad(
    const float* __restrict__ src, ushort_t* __restrict__ dh, int Csrc, int Cdst)
{
  const int r = blockIdx.x;
  for (int c = threadIdx.x; c < Cdst; c += 256) {
    float v = (c < Csrc) ? src[(size_t)r * Csrc + c] : 0.f;
    dh[(size_t)r * Cdst + c] = f2bf(v);
  }
}

// ---------------- vin input: hi plane of concat(0, vertice[:-1]) - tmpl ----------------
__global__ __launch_bounds__(256) void prep_vin(const float* __restrict__ vertice,
                                                const float* __restrict__ tmpl,
                                                ushort_t* __restrict__ dh) {
  const int t = blockIdx.x;
  for (int k = threadIdx.x; k < KVIN; k += 256) {
    float v = 0.f;
    if (t > 0 && k < 15069) v = vertice[(size_t)(t - 1) * 15069 + k] - tmpl[k];
    dh[(size_t)t * KVIN + k] = f2bf(v);
  }
}

__global__ void prep_bias2(const float* __restrict__ one_hot, const float* __restrict__ W_obj,
                           const float* __restrict__ b_vm, float* __restrict__ bias2) {
  int d = blockIdx.x * 256 + threadIdx.x;
  if (d < 1024) {
    float s = 0.f;
    #pragma unroll
    for (int j = 0; j < 8; ++j) s += one_hot[j] * W_obj[d * 8 + j];
    bias2[d] = b_vm[d] + s;
  }
}

__global__ void prep_bias3(const float* __restrict__ b_vr, const float* __restrict__ tmpl,
                           float* __restrict__ bias3, int n) {
  int v = blockIdx.x * 256 + threadIdx.x;
  if (v < n) bias3[v] = b_vr[v] + tmpl[v];
}

// sum 16 vin split-K partials + bias2 + PE -> x (f32 + hi plane)
__global__ __launch_bounds__(256) void reduce_pe(const float* __restrict__ part,
                                                 const float* __restrict__ bias2,
                                                 float* __restrict__ x,
                                                 ushort_t* __restrict__ xh) {
  const int t = blockIdx.x;
  const float PECOEF = -9.210340371976184f / 512.f;  // -ln(10000)/512
  const int p = t % 25;
  for (int d = threadIdx.x; d < 1024; d += 256) {
    float s = bias2[d];
    #pragma unroll
    for (int z = 0; z < 16; ++z) s += part[(size_t)z * 524288 + (size_t)t * 1024 + d];
    float arg = (float)p * expf((float)(d >> 1) * PECOEF);
    s += (d & 1) ? cosf(arg) : sinf(arg);
    const size_t idx = (size_t)t * 1024 + d;
    x[idx] = s;
    xh[idx] = f2bf(s);
  }
}

// V transpose from qkv split-K parts: vth[d][s] = bf16(sum_z part[z][s][2048+d] + bias)
__global__ __launch_bounds__(256) void vT_parts(const float* __restrict__ part,
                                                const float* __restrict__ bias,
                                                ushort_t* __restrict__ vth) {
  __shared__ float tile[32][33];
  const int s0 = blockIdx.x * 32, d0 = blockIdx.y * 32;
  const int tx = threadIdx.x & 31, ty = threadIdx.x >> 5;  // 32 x 8
  for (int r = ty; r < 32; r += 8) {
    float v = bias[2048 + d0 + tx];
    #pragma unroll
    for (int z = 0; z < 4; ++z)
      v += part[(size_t)z * 1572864 + (size_t)(s0 + r) * 3072 + 2048 + d0 + tx];
    tile[r][tx] = v;
  }
  __syncthreads();
  for (int r = ty; r < 32; r += 8)
    vth[(size_t)(d0 + r) * 512 + s0 + tx] = f2bf(tile[tx][r]);
}

// row softmax with ALIBI + causal; reads raw scores f32, writes attn hi plane
__global__ __launch_bounds__(256) void softmax_alibi(const float* __restrict__ scores,
                                                     ushort_t* __restrict__ ah) {
  const int i = blockIdx.x, h = blockIdx.y;
  const size_t rb = ((size_t)h * 512 + i) * 512;
  const float* row = scores + rb;
  const int tid = threadIdx.x;
  const int len = i + 1;
  const float sl = exp2f(-2.f * (float)(h + 1));
  const int j0 = tid, j1 = tid + 256;
  float v0 = -INFINITY, v1 = -INFINITY;
  if (j0 < len) v0 = row[j0] * 0.0625f - sl * (float)((i - j0) / 25);
  if (j1 < len) v1 = row[j1] * 0.0625f - sl * (float)((i - j1) / 25);
  __shared__ float red[4];
  float m = blockReduceMax256(fmaxf(v0, v1), red);
  float e0 = (j0 < len) ? expf(v0 - m) : 0.f;
  float e1 = (j1 < len) ? expf(v1 - m) : 0.f;
  float s = blockReduceSum256(e0 + e1, red);
  float inv = 1.f / s;
  ah[rb + j0] = f2bf(e0 * inv);
  ah[rb + j1] = f2bf(e1 * inv);
}

// ---------------- host-side launch ----------------
extern "C" void kernel_launch(void* const* d_in, const int* in_sizes, int n_in,
                              void* d_out, int out_size, void* d_ws, size_t ws_size,
                              hipStream_t stream) {
  const float* audio   = (const float*)d_in[0];
  const float* vertice = (const float*)d_in[1];
  const float* tmpl    = (const float*)d_in[2];
  const float* one_hot = (const float*)d_in[3];
  const float* W_af    = (const float*)d_in[4];
  const float* b_af    = (const float*)d_in[5];
  const float* W_vm    = (const float*)d_in[6];
  const float* b_vm    = (const float*)d_in[7];
  const float* W_obj   = (const float*)d_in[8];
  const float* Wqkv_sa = (const float*)d_in[9];
  const float* bqkv_sa = (const float*)d_in[10];
  const float* Wo_sa   = (const float*)d_in[11];
  const float* bo_sa   = (const float*)d_in[12];
  const float* Wqkv_ca = (const float*)d_in[13];
  const float* bqkv_ca = (const float*)d_in[14];
  const float* Wo_ca   = (const float*)d_in[15];
  const float* bo_ca   = (const float*)d_in[16];
  const float* W1      = (const float*)d_in[17];
  const float* b1      = (const float*)d_in[18];
  const float* W2      = (const float*)d_in[19];
  const float* b2      = (const float*)d_in[20];
  const float* g1      = (const float*)d_in[21];
  const float* be1     = (const float*)d_in[22];
  const float* g2      = (const float*)d_in[23];
  const float* be2     = (const float*)d_in[24];
  const float* g3      = (const float*)d_in[25];
  const float* be3     = (const float*)d_in[26];
  const float* W_vr    = (const float*)d_in[27];
  const float* b_vr    = (const float*)d_in[28];
  float* out = (float*)d_out;

  // ---- workspace carve (floats), total ~100 MB ----
  float* base = (float*)d_ws;
  float* apF    = base;                  // 512*15360 us  = 3,932,160 fl
  float* wvmF   = apF + 3932160;         // 1024*15360 us = 7,864,320 fl
  float* part   = wvmF + 7864320;        // 16*524288     = 8,388,608 fl
  float* x      = part + 8388608;        // 524,288
  float* xhF    = x + 524288;            // 262,144 (512*1024 us)
  float* audF   = xhF + 262144;          // 196,608 (512*768 us)
  float* hidF   = audF + 196608;         // 262,144
  float* qkvF   = hidF + 262144;         // 786,432 (512*3072 us)
  float* vtF    = qkvF + 786432;         // 262,144 (1024*512 us)
  float* scores = vtF + 262144;          // 1,048,576
  float* attF   = scores + 1048576;      // 524,288 (4*512*512 us)
  float* ctxF   = attF + 524288;         // 262,144
  float* cvF    = ctxF + 262144;         // 262,144
  float* h1F    = cvF + 262144;          // 524,288 (512*2048 us)
  float* bias2  = h1F + 524288;          // 1,024
  float* bias3  = bias2 + 1024;          // 15,072

  ushort_t* Aph  = (ushort_t*)apF;
  ushort_t* Wvmh = (ushort_t*)wvmF;
  ushort_t* xh   = (ushort_t*)xhF;
  ushort_t* audh = (ushort_t*)audF;
  ushort_t* hidh = (ushort_t*)hidF;
  ushort_t* qkvh = (ushort_t*)qkvF;
  ushort_t* vth  = (ushort_t*)vtF;
  ushort_t* atth = (ushort_t*)attF;
  ushort_t* ctxh = (ushort_t*)ctxF;
  ushort_t* cvh  = (ushort_t*)cvF;
  ushort_t* h1h  = (ushort_t*)h1F;

  // ---- prep ----
  prep_bias2<<<4, 256, 0, stream>>>(one_hot, W_obj, b_vm, bias2);
  prep_bias3<<<(15069 + 255) / 256, 256, 0, stream>>>(b_vr, tmpl, bias3, 15069);
  prep_vin<<<512, 256, 0, stream>>>(vertice, tmpl, Aph);
  split_pad<<<1024, 256, 0, stream>>>(W_vm, Wvmh, 15069, KVIN);

  // ---- vin = Ap @ Wvm^T  (split-K x16, 512 blocks) ----
  glds<true, false, false, false><<<dim3(8, 4, 16), 256, 0, stream>>>(
      Aph, Wvmh, nullptr, part, nullptr,
      1024, KVIN, KVIN, KVIN, 1024, 960, 0, 0, 524288);
  reduce_pe<<<512, 256, 0, stream>>>(part, bias2, x, xh);

  // ---- hidden = audio @ W_af^T + b_af ----
  split_pad<<<512, 256, 0, stream>>>(audio, audh, 768, 768);
  glds<false, false, false, false><<<dim3(8, 4, 6), 256, 0, stream>>>(
      audh, W_af, nullptr, part, nullptr,
      1024, 768, 768, 768, 1024, 128, 0, 0, 524288);
  combine<false><<<512, 256, 0, stream>>>(part, b_af, hidh, 6, 524288, 131072, 256);

  // ---- self attention ----
  glds<false, false, false, false><<<dim3(24, 4, 4), 256, 0, stream>>>(
      xh, Wqkv_sa, nullptr, part, nullptr,
      3072, 1024, 1024, 1024, 3072, 256, 0, 0, 1572864);
  combine<false><<<1536, 256, 0, stream>>>(part, bqkv_sa, qkvh, 4, 1572864, 393216, 768);
  vT_parts<<<dim3(16, 32), 256, 0, stream>>>(part, bqkv_sa, vth);
  // scores[h] = q_h @ k_h^T : z = head via kChunk=256 (causal tiles only)
  glds<true, false, true, false><<<dim3(4, 4, 4), 256, 0, stream>>>(
      qkvh, qkvh + 1024, nullptr, scores, nullptr,
      512, 1024, 3072, 3072, 512, 256, 0, 0, 262144);
  softmax_alibi<<<dim3(512, 4), 256, 0, stream>>>(scores, atth);
  // ctx[h] = attn_h @ vT_h^T, bf16 out directly
  glds<true, false, false, true><<<dim3(2, 4, 4), 256, 0, stream>>>(
      atth, vth, nullptr, nullptr, ctxh,
      256, 512, 512, 512, 1024, 0, 262144, 131072, 256);
  // out proj + LN
  glds<false, false, false, false><<<dim3(8, 4, 8), 256, 0, stream>>>(
      ctxh, Wo_sa, nullptr, part, nullptr,
      1024, 1024, 1024, 1024, 1024, 128, 0, 0, 524288);
  ln_parts<<<512, 256, 0, stream>>>(part, 8, bo_sa, x, xh, g1, be1);

  // ---- cross attention: bool mask == identity -> V then O projection ----
  glds<false, false, false, false><<<dim3(8, 4, 8), 256, 0, stream>>>(
      hidh, Wqkv_ca + (size_t)2048 * 1024, nullptr, part, nullptr,
      1024, 1024, 1024, 1024, 1024, 128, 0, 0, 524288);
  combine<false><<<512, 256, 0, stream>>>(part, bqkv_ca + 2048, cvh, 8, 524288, 131072, 256);
  glds<false, false, false, false><<<dim3(8, 4, 8), 256, 0, stream>>>(
      cvh, Wo_ca, nullptr, part, nullptr,
      1024, 1024, 1024, 1024, 1024, 128, 0, 0, 524288);
  ln_parts<<<512, 256, 0, stream>>>(part, 8, bo_ca, x, xh, g2, be2);

  // ---- feed forward ----
  glds<false, false, false, false><<<dim3(16, 4, 4), 256, 0, stream>>>(
      xh, W1, nullptr, part, nullptr,
      2048, 1024, 1024, 1024, 2048, 256, 0, 0, 1048576);
  combine<true><<<1024, 256, 0, stream>>>(part, b1, h1h, 4, 1048576, 262144, 512);
  glds<false, false, false, false><<<dim3(8, 4, 8), 256, 0, stream>>>(
      h1h, W2, nullptr, part, nullptr,
      1024, 2048, 2048, 2048, 1024, 256, 0, 0, 524288);
  ln_parts<<<512, 256, 0, stream>>>(part, 8, b2, x, xh, g3, be3);

  // ---- final projection: out = x @ W_vr^T + (b_vr + tmpl)  (fp32 B fused) ----
  glds<false, true, false, false><<<dim3(118, 4, 1), 256, 0, stream>>>(
      xh, W_vr, bias3, out, nullptr,
      15069, 1024, 1024, 1024, 15069, 0, 0, 0, 0);
}

// Round 7
// 426.983 us; speedup vs baseline: 1.1893x; 1.1893x over previous
//
#include <hip/hip_runtime.h>
#include <math.h>

typedef __attribute__((ext_vector_type(8))) short short8;
typedef __attribute__((ext_vector_type(4))) float f32x4;
typedef unsigned short ushort_t;

#define KVIN 15360   // 15069 padded to 960*16 (split-K x16, K%32==0)

__device__ __forceinline__ ushort_t f2bf(float f) {
  unsigned u = __float_as_uint(f);
  return (ushort_t)((u + 0x7fffu + ((u >> 16) & 1u)) >> 16);  // RNE
}
__device__ __forceinline__ float bf2f(ushort_t h) {
  return __uint_as_float(((unsigned)h) << 16);
}

// ---------------- block reduction helpers (256-thread blocks) ----------------
__device__ __forceinline__ float blockReduceSum256(float v, float* red) {
  #pragma unroll
  for (int o = 32; o; o >>= 1) v += __shfl_xor(v, o);
  int wid = threadIdx.x >> 6, lane = threadIdx.x & 63;
  if (lane == 0) red[wid] = v;
  __syncthreads();
  v = red[0] + red[1] + red[2] + red[3];
  __syncthreads();
  return v;
}
__device__ __forceinline__ float blockReduceMax256(float v, float* red) {
  #pragma unroll
  for (int o = 32; o; o >>= 1) v = fmaxf(v, __shfl_xor(v, o));
  int wid = threadIdx.x >> 6, lane = threadIdx.x & 63;
  if (lane == 0) red[wid] = v;
  __syncthreads();
  v = fmaxf(fmaxf(red[0], red[1]), fmaxf(red[2], red[3]));
  __syncthreads();
  return v;
}

// ============ 1-pass bf16 MFMA GEMM, 128x128 tile, conflict-free LDS ============
// C = A @ B^T (+bias). A: bf16. B: bf16 (BF16B) or fp32 (converted in staging).
// M = 512 exact. N ragged (guarded). K%32==0; kChunk%32==0 (split-K via z).
// ZFAST: grid is (z, mTile, nTile) so blocks sharing a K-slice land on one XCD
// (linear id % 8 == z % 8): A+B slice (~3 MB) fits that XCD's 4 MB L2.
// LDS layout: 16B unit (row,q) at unit-idx (row>>4)*64 + q*16 + (row&15)
//   -> frag read addr = base + 16*lane (conflict-free; SQ_LDS_BANK_CONFLICT==0 in R6);
//      stager thread t writes units {t, t+256} at bytes {16t, 16t+4096}.
template <bool BF16B, bool BIAS, bool CAUSAL, bool POUT, bool ZFAST>
__global__ __launch_bounds__(256, 2) void glds(
    const ushort_t* __restrict__ A, const void* __restrict__ Bv,
    const float* __restrict__ bias, float* __restrict__ C, ushort_t* __restrict__ Ch,
    int N, int K, int lda, int ldb, int ldc,
    int kChunk, long aZ, long bZ, long cZ)
{
  const int z  = ZFAST ? blockIdx.x : blockIdx.z;
  const int m0 = blockIdx.y * 128;
  const int n0 = (ZFAST ? blockIdx.z : blockIdx.x) * 128;
  if (CAUSAL && n0 > m0 + 127) return;   // tile fully above diagonal
  __shared__ ushort_t sA[4096], sB[4096];   // 512 units x 8 bf16 each
  const int tid = threadIdx.x;
  const int kBeg = kChunk ? z * kChunk : 0;
  const int kEnd = kChunk ? kBeg + kChunk : K;
  A += (size_t)z * aZ;
  const ushort_t* Bh = (const ushort_t*)Bv;
  const float*    Bf = (const float*)Bv;
  if (BF16B) Bh += (size_t)z * bZ; else Bf += (size_t)z * bZ;
  C += (size_t)z * cZ;
  if (POUT) Ch += (size_t)z * cZ;

  // staging map: thread t -> unit t (rows 0-63) and t+256 (rows 64-127)
  const int r0 = ((tid >> 6) << 4) | (tid & 15);   // unit t -> row
  const int q0 = (tid >> 4) & 3;                   // k-chunk within 32
  const int r1 = r0 + 64;
  const ushort_t* pA0 = A + (size_t)(m0 + r0) * lda + (q0 << 3);
  const ushort_t* pA1 = A + (size_t)(m0 + r1) * lda + (q0 << 3);
  const int gn0 = n0 + r0, gn1 = n0 + r1;
  const bool bok0 = gn0 < N, bok1 = gn1 < N;
  const ushort_t* pB0h = Bh + (size_t)gn0 * ldb + (q0 << 3);
  const ushort_t* pB1h = Bh + (size_t)gn1 * ldb + (q0 << 3);
  const float*    pB0f = Bf + (size_t)gn0 * ldb + (q0 << 3);
  const float*    pB1f = Bf + (size_t)gn1 * ldb + (q0 << 3);

  // waves 2x2, each 64x64
  const int lane = tid & 63;
  const int wrb = (tid >> 7) & 1;
  const int wcb = (tid >> 6) & 1;
  const int fr = lane & 15, fq = lane >> 4;

  f32x4 acc[4][4] = {};
  const short8 z8 = {0, 0, 0, 0, 0, 0, 0, 0};
  const float4 z4 = make_float4(0.f, 0.f, 0.f, 0.f);
  short8 ra0, ra1, rb0, rb1;
  float4 f00, f01, f10, f11;

  ra0 = *(const short8*)(pA0 + kBeg);
  ra1 = *(const short8*)(pA1 + kBeg);
  if (BF16B) {
    rb0 = bok0 ? *(const short8*)(pB0h + kBeg) : z8;
    rb1 = bok1 ? *(const short8*)(pB1h + kBeg) : z8;
  } else {
    f00 = bok0 ? *(const float4*)(pB0f + kBeg) : z4;
    f01 = bok0 ? *(const float4*)(pB0f + kBeg + 4) : z4;
    f10 = bok1 ? *(const float4*)(pB1f + kBeg) : z4;
    f11 = bok1 ? *(const float4*)(pB1f + kBeg + 4) : z4;
  }

  for (int k0 = kBeg; k0 < kEnd; k0 += 32) {
    __syncthreads();  // prior iter's fragment reads complete
    *(short8*)&sA[tid << 3] = ra0;
    *(short8*)&sA[(tid + 256) << 3] = ra1;
    if (BF16B) {
      *(short8*)&sB[tid << 3] = rb0;
      *(short8*)&sB[(tid + 256) << 3] = rb1;
    } else {
      short8 s0, s1;
      #pragma unroll
      for (int j = 0; j < 4; ++j) {
        s0[j] = (short)f2bf(f00[j]); s0[j + 4] = (short)f2bf(f01[j]);
        s1[j] = (short)f2bf(f10[j]); s1[j + 4] = (short)f2bf(f11[j]);
      }
      *(short8*)&sB[tid << 3] = s0;
      *(short8*)&sB[(tid + 256) << 3] = s1;
    }
    if (k0 + 32 < kEnd) {  // prefetch next k-step
      const int k = k0 + 32;
      ra0 = *(const short8*)(pA0 + k);
      ra1 = *(const short8*)(pA1 + k);
      if (BF16B) {
        rb0 = bok0 ? *(const short8*)(pB0h + k) : z8;
        rb1 = bok1 ? *(const short8*)(pB1h + k) : z8;
      } else {
        f00 = bok0 ? *(const float4*)(pB0f + k) : z4;
        f01 = bok0 ? *(const float4*)(pB0f + k + 4) : z4;
        f10 = bok1 ? *(const float4*)(pB1f + k) : z4;
        f11 = bok1 ? *(const float4*)(pB1f + k + 4) : z4;
      }
    }
    __syncthreads();  // writes visible

    short8 fa[4], fb[4];
    #pragma unroll
    for (int f = 0; f < 4; ++f)
      fa[f] = *(const short8*)&sA[((((wrb << 2) + f) << 9) | (lane << 3))];
    #pragma unroll
    for (int g = 0; g < 4; ++g)
      fb[g] = *(const short8*)&sB[((((wcb << 2) + g) << 9) | (lane << 3))];
    #pragma unroll
    for (int f = 0; f < 4; ++f)
      #pragma unroll
      for (int g = 0; g < 4; ++g)
        acc[f][g] = __builtin_amdgcn_mfma_f32_16x16x32_bf16(fa[f], fb[g], acc[f][g], 0, 0, 0);
  }

  // epilogue: C/D layout col=lane&15, row=(lane>>4)*4+reg
  #pragma unroll
  for (int f = 0; f < 4; ++f) {
    const int gm = m0 + (wrb << 6) + f * 16 + fq * 4;
    #pragma unroll
    for (int g = 0; g < 4; ++g) {
      const int gn = n0 + (wcb << 6) + g * 16 + fr;
      if (gn < N) {
        #pragma unroll
        for (int i = 0; i < 4; ++i) {
          float v = acc[f][g][i];
          if (BIAS) v += bias[gn];
          const size_t o = (size_t)(gm + i) * ldc + gn;
          if (POUT) Ch[o] = f2bf(v);
          else      C[o] = v;
        }
      }
    }
  }
}

// ---------------- split-K combine: outh = bf16(sum_z part[z] + bias (+relu)) ----------------
template <bool RELU>
__global__ __launch_bounds__(256) void combine(
    const float* __restrict__ part, const float* __restrict__ bias,
    ushort_t* __restrict__ outh, int nz, long zstride, int total4, int N4)
{
  const int i = blockIdx.x * 256 + threadIdx.x;
  if (i >= total4) return;
  float4 s = ((const float4*)bias)[i % N4];
  for (int z = 0; z < nz; ++z) {
    float4 p = ((const float4*)(part + (size_t)z * zstride))[i];
    s.x += p.x; s.y += p.y; s.z += p.z; s.w += p.w;
  }
  if (RELU) {
    s.x = fmaxf(s.x, 0.f); s.y = fmaxf(s.y, 0.f);
    s.z = fmaxf(s.z, 0.f); s.w = fmaxf(s.w, 0.f);
  }
  ((ushort4*)outh)[i] = make_ushort4(f2bf(s.x), f2bf(s.y), f2bf(s.z), f2bf(s.w));
}

// ---------------- fused split-K combine + residual + LayerNorm ----------------
__global__ __launch_bounds__(256) void ln_parts(
    const float* __restrict__ part, int nz, const float* __restrict__ bias,
    float* __restrict__ x, ushort_t* __restrict__ xh,
    const float* __restrict__ g, const float* __restrict__ b)
{
  const int t = blockIdx.x, tid = threadIdx.x;
  float4 y = ((const float4*)(x + (size_t)t * 1024))[tid];
  float4 s = ((const float4*)bias)[tid];
  for (int z = 0; z < nz; ++z) {
    float4 p = ((const float4*)(part + (size_t)z * 524288 + (size_t)t * 1024))[tid];
    s.x += p.x; s.y += p.y; s.z += p.z; s.w += p.w;
  }
  y.x += s.x; y.y += s.y; y.z += s.z; y.w += s.w;
  __shared__ float red[4];
  float sum = blockReduceSum256(y.x + y.y + y.z + y.w, red);
  const float m = sum * (1.f / 1024.f);
  float dx = y.x - m, dy = y.y - m, dz = y.z - m, dw = y.w - m;
  float q = blockReduceSum256(dx * dx + dy * dy + dz * dz + dw * dw, red);
  const float rs = rsqrtf(q * (1.f / 1024.f) + 1e-5f);
  float4 gg = ((const float4*)g)[tid], bb = ((const float4*)b)[tid];
  float4 o;
  o.x = dx * rs * gg.x + bb.x;
  o.y = dy * rs * gg.y + bb.y;
  o.z = dz * rs * gg.z + bb.z;
  o.w = dw * rs * gg.w + bb.w;
  ((float4*)(x + (size_t)t * 1024))[tid] = o;
  ((ushort4*)xh)[t * 256 + tid] = make_ushort4(f2bf(o.x), f2bf(o.y), f2bf(o.z), f2bf(o.w));
}

// ---------------- fp32 (R x Csrc) -> bf16 plane (R x Cdst), zero-padded ----------------
__global__ __launch_bounds__(256) void split_pad(
    const float* __restrict__ src, ushort_t* __restrict__ dh, int Csrc, int Cdst)
{
  const int r = blockIdx.x;
  for (int c = threadIdx.x; c < Cdst; c += 256) {
    float v = (c < Csrc) ? src[(size_t)r * Csrc + c] : 0.f;
    dh[(size_t)r * Cdst + c] = f2bf(v);
  }
}

// ---------------- vin input: bf16 of concat(0, vertice[:-1]) - tmpl ----------------
__global__ __launch_bounds__(256) void prep_vin(const float* __restrict__ vertice,
                                                const float* __restrict__ tmpl,
                                                ushort_t* __restrict__ dh) {
  const int t = blockIdx.x;
  for (int k = threadIdx.x; k < KVIN; k += 256) {
    float v = 0.f;
    if (t > 0 && k < 15069) v = vertice[(size_t)(t - 1) * 15069 + k] - tmpl[k];
    dh[(size_t)t * KVIN + k] = f2bf(v);
  }
}

__global__ void prep_bias2(const float* __restrict__ one_hot, const float* __restrict__ W_obj,
                           const float* __restrict__ b_vm, float* __restrict__ bias2) {
  int d = blockIdx.x * 256 + threadIdx.x;
  if (d < 1024) {
    float s = 0.f;
    #pragma unroll
    for (int j = 0; j < 8; ++j) s += one_hot[j] * W_obj[d * 8 + j];
    bias2[d] = b_vm[d] + s;
  }
}

__global__ void prep_bias3(const float* __restrict__ b_vr, const float* __restrict__ tmpl,
                           float* __restrict__ bias3, int n) {
  int v = blockIdx.x * 256 + threadIdx.x;
  if (v < n) bias3[v] = b_vr[v] + tmpl[v];
}

// sum 16 vin split-K partials + bias2 + PE -> x (f32 + bf16)
__global__ __launch_bounds__(256) void reduce_pe(const float* __restrict__ part,
                                                 const float* __restrict__ bias2,
                                                 float* __restrict__ x,
                                                 ushort_t* __restrict__ xh) {
  const int t = blockIdx.x;
  const float PECOEF = -9.210340371976184f / 512.f;  // -ln(10000)/512
  const int p = t % 25;
  for (int d = threadIdx.x; d < 1024; d += 256) {
    float s = bias2[d];
    #pragma unroll
    for (int z = 0; z < 16; ++z) s += part[(size_t)z * 524288 + (size_t)t * 1024 + d];
    float arg = (float)p * expf((float)(d >> 1) * PECOEF);
    s += (d & 1) ? cosf(arg) : sinf(arg);
    const size_t idx = (size_t)t * 1024 + d;
    x[idx] = s;
    xh[idx] = f2bf(s);
  }
}

// V transpose from qkv split-K parts: vth[d][s] = bf16(sum_z part[z][s][2048+d] + bias)
__global__ __launch_bounds__(256) void vT_parts(const float* __restrict__ part,
                                                const float* __restrict__ bias,
                                                ushort_t* __restrict__ vth) {
  __shared__ float tile[32][33];
  const int s0 = blockIdx.x * 32, d0 = blockIdx.y * 32;
  const int tx = threadIdx.x & 31, ty = threadIdx.x >> 5;  // 32 x 8
  for (int r = ty; r < 32; r += 8) {
    float v = bias[2048 + d0 + tx];
    #pragma unroll
    for (int z = 0; z < 4; ++z)
      v += part[(size_t)z * 1572864 + (size_t)(s0 + r) * 3072 + 2048 + d0 + tx];
    tile[r][tx] = v;
  }
  __syncthreads();
  for (int r = ty; r < 32; r += 8)
    vth[(size_t)(d0 + r) * 512 + s0 + tx] = f2bf(tile[tx][r]);
}

// row softmax with ALIBI + causal; reads raw scores f32, writes attn bf16
__global__ __launch_bounds__(256) void softmax_alibi(const float* __restrict__ scores,
                                                     ushort_t* __restrict__ ah) {
  const int i = blockIdx.x, h = blockIdx.y;
  const size_t rb = ((size_t)h * 512 + i) * 512;
  const float* row = scores + rb;
  const int tid = threadIdx.x;
  const int len = i + 1;
  const float sl = exp2f(-2.f * (float)(h + 1));
  const int j0 = tid, j1 = tid + 256;
  float v0 = -INFINITY, v1 = -INFINITY;
  if (j0 < len) v0 = row[j0] * 0.0625f - sl * (float)((i - j0) / 25);
  if (j1 < len) v1 = row[j1] * 0.0625f - sl * (float)((i - j1) / 25);
  __shared__ float red[4];
  float m = blockReduceMax256(fmaxf(v0, v1), red);
  float e0 = (j0 < len) ? expf(v0 - m) : 0.f;
  float e1 = (j1 < len) ? expf(v1 - m) : 0.f;
  float s = blockReduceSum256(e0 + e1, red);
  float inv = 1.f / s;
  ah[rb + j0] = f2bf(e0 * inv);
  ah[rb + j1] = f2bf(e1 * inv);
}

// ---------------- host-side launch ----------------
extern "C" void kernel_launch(void* const* d_in, const int* in_sizes, int n_in,
                              void* d_out, int out_size, void* d_ws, size_t ws_size,
                              hipStream_t stream) {
  const float* audio   = (const float*)d_in[0];
  const float* vertice = (const float*)d_in[1];
  const float* tmpl    = (const float*)d_in[2];
  const float* one_hot = (const float*)d_in[3];
  const float* W_af    = (const float*)d_in[4];
  const float* b_af    = (const float*)d_in[5];
  const float* W_vm    = (const float*)d_in[6];
  const float* b_vm    = (const float*)d_in[7];
  const float* W_obj   = (const float*)d_in[8];
  const float* Wqkv_sa = (const float*)d_in[9];
  const float* bqkv_sa = (const float*)d_in[10];
  const float* Wo_sa   = (const float*)d_in[11];
  const float* bo_sa   = (const float*)d_in[12];
  const float* Wqkv_ca = (const float*)d_in[13];
  const float* bqkv_ca = (const float*)d_in[14];
  const float* Wo_ca   = (const float*)d_in[15];
  const float* bo_ca   = (const float*)d_in[16];
  const float* W1      = (const float*)d_in[17];
  const float* b1      = (const float*)d_in[18];
  const float* W2      = (const float*)d_in[19];
  const float* b2      = (const float*)d_in[20];
  const float* g1      = (const float*)d_in[21];
  const float* be1     = (const float*)d_in[22];
  const float* g2      = (const float*)d_in[23];
  const float* be2     = (const float*)d_in[24];
  const float* g3      = (const float*)d_in[25];
  const float* be3     = (const float*)d_in[26];
  const float* W_vr    = (const float*)d_in[27];
  const float* b_vr    = (const float*)d_in[28];
  float* out = (float*)d_out;

  // ---- workspace carve (floats), total ~100 MB ----
  float* base = (float*)d_ws;
  float* apF    = base;                  // 512*15360 us  = 3,932,160 fl
  float* wvmF   = apF + 3932160;         // 1024*15360 us = 7,864,320 fl (Wvm, then Wvr after vin)
  float* part   = wvmF + 7864320;        // 16*524288     = 8,388,608 fl
  float* x      = part + 8388608;        // 524,288
  float* xhF    = x + 524288;            // 262,144 (512*1024 us)
  float* audF   = xhF + 262144;          // 196,608 (512*768 us)
  float* hidF   = audF + 196608;         // 262,144
  float* qkvF   = hidF + 262144;         // 786,432 (512*3072 us)
  float* vtF    = qkvF + 786432;         // 262,144 (1024*512 us)
  float* scores = vtF + 262144;          // 1,048,576
  float* attF   = scores + 1048576;      // 524,288 (4*512*512 us)
  float* ctxF   = attF + 524288;         // 262,144
  float* cvF    = ctxF + 262144;         // 262,144
  float* h1F    = cvF + 262144;          // 524,288 (512*2048 us)
  float* bias2  = h1F + 524288;          // 1,024
  float* bias3  = bias2 + 1024;          // 15,072

  ushort_t* Aph  = (ushort_t*)apF;
  ushort_t* Wvmh = (ushort_t*)wvmF;
  ushort_t* Wvrh = (ushort_t*)wvmF;      // alias: Wvm dead after vin GEMM
  ushort_t* xh   = (ushort_t*)xhF;
  ushort_t* audh = (ushort_t*)audF;
  ushort_t* hidh = (ushort_t*)hidF;
  ushort_t* qkvh = (ushort_t*)qkvF;
  ushort_t* vth  = (ushort_t*)vtF;
  ushort_t* atth = (ushort_t*)attF;
  ushort_t* ctxh = (ushort_t*)ctxF;
  ushort_t* cvh  = (ushort_t*)cvF;
  ushort_t* h1h  = (ushort_t*)h1F;

  // ---- prep ----
  prep_bias2<<<4, 256, 0, stream>>>(one_hot, W_obj, b_vm, bias2);
  prep_bias3<<<(15069 + 255) / 256, 256, 0, stream>>>(b_vr, tmpl, bias3, 15069);
  prep_vin<<<512, 256, 0, stream>>>(vertice, tmpl, Aph);
  split_pad<<<1024, 256, 0, stream>>>(W_vm, Wvmh, 15069, KVIN);

  // ---- vin = Ap @ Wvm^T  (split-K x16, z-fastest grid for XCD/L2 locality) ----
  glds<true, false, false, false, true><<<dim3(16, 4, 8), 256, 0, stream>>>(
      Aph, Wvmh, nullptr, part, nullptr,
      1024, KVIN, KVIN, KVIN, 1024, 960, 0, 0, 524288);
  reduce_pe<<<512, 256, 0, stream>>>(part, bias2, x, xh);

  // Wvr bf16 plane (reuse wvm region; Wvm dead after vin GEMM above)
  split_pad<<<15069, 256, 0, stream>>>(W_vr, Wvrh, 1024, 1024);

  // ---- hidden = audio @ W_af^T + b_af ----
  split_pad<<<512, 256, 0, stream>>>(audio, audh, 768, 768);
  glds<false, false, false, false, false><<<dim3(8, 4, 6), 256, 0, stream>>>(
      audh, W_af, nullptr, part, nullptr,
      1024, 768, 768, 768, 1024, 128, 0, 0, 524288);
  combine<false><<<512, 256, 0, stream>>>(part, b_af, hidh, 6, 524288, 131072, 256);

  // ---- self attention ----
  glds<false, false, false, false, false><<<dim3(24, 4, 4), 256, 0, stream>>>(
      xh, Wqkv_sa, nullptr, part, nullptr,
      3072, 1024, 1024, 1024, 3072, 256, 0, 0, 1572864);
  combine<false><<<1536, 256, 0, stream>>>(part, bqkv_sa, qkvh, 4, 1572864, 393216, 768);
  vT_parts<<<dim3(16, 32), 256, 0, stream>>>(part, bqkv_sa, vth);
  // scores[h] = q_h @ k_h^T : z = head via kChunk=256 (causal tiles only)
  glds<true, false, true, false, false><<<dim3(4, 4, 4), 256, 0, stream>>>(
      qkvh, qkvh + 1024, nullptr, scores, nullptr,
      512, 1024, 3072, 3072, 512, 256, 0, 0, 262144);
  softmax_alibi<<<dim3(512, 4), 256, 0, stream>>>(scores, atth);
  // ctx[h] = attn_h @ vT_h^T, bf16 out directly
  glds<true, false, false, true, false><<<dim3(2, 4, 4), 256, 0, stream>>>(
      atth, vth, nullptr, nullptr, ctxh,
      256, 512, 512, 512, 1024, 0, 262144, 131072, 256);
  // out proj + LN
  glds<false, false, false, false, false><<<dim3(8, 4, 8), 256, 0, stream>>>(
      ctxh, Wo_sa, nullptr, part, nullptr,
      1024, 1024, 1024, 1024, 1024, 128, 0, 0, 524288);
  ln_parts<<<512, 256, 0, stream>>>(part, 8, bo_sa, x, xh, g1, be1);

  // ---- cross attention: bool mask == identity -> V then O projection ----
  glds<false, false, false, false, false><<<dim3(8, 4, 8), 256, 0, stream>>>(
      hidh, Wqkv_ca + (size_t)2048 * 1024, nullptr, part, nullptr,
      1024, 1024, 1024, 1024, 1024, 128, 0, 0, 524288);
  combine<false><<<512, 256, 0, stream>>>(part, bqkv_ca + 2048, cvh, 8, 524288, 131072, 256);
  glds<false, false, false, false, false><<<dim3(8, 4, 8), 256, 0, stream>>>(
      cvh, Wo_ca, nullptr, part, nullptr,
      1024, 1024, 1024, 1024, 1024, 128, 0, 0, 524288);
  ln_parts<<<512, 256, 0, stream>>>(part, 8, bo_ca, x, xh, g2, be2);

  // ---- feed forward ----
  glds<false, false, false, false, false><<<dim3(16, 4, 4), 256, 0, stream>>>(
      xh, W1, nullptr, part, nullptr,
      2048, 1024, 1024, 1024, 2048, 256, 0, 0, 1048576);
  combine<true><<<1024, 256, 0, stream>>>(part, b1, h1h, 4, 1048576, 262144, 512);
  glds<false, false, false, false, false><<<dim3(8, 4, 8), 256, 0, stream>>>(
      h1h, W2, nullptr, part, nullptr,
      1024, 2048, 2048, 2048, 1024, 256, 0, 0, 524288);
  ln_parts<<<512, 256, 0, stream>>>(part, 8, b2, x, xh, g3, be3);

  // ---- final projection: out = x @ W_vr^T + (b_vr + tmpl)  (pre-split bf16 B) ----
  glds<true, true, false, false, false><<<dim3(118, 4, 1), 256, 0, stream>>>(
      xh, Wvrh, bias3, out, nullptr,
      15069, 1024, 1024, 1024, 15069, 0, 0, 0, 0);
}

// Round 8
// 371.086 us; speedup vs baseline: 1.3685x; 1.1506x over previous
//
#include <hip/hip_runtime.h>
#include <math.h>

typedef __attribute__((ext_vector_type(8))) short short8;
typedef __attribute__((ext_vector_type(4))) float f32x4;
typedef unsigned short ushort_t;

#define KVIN 15360   // 15069 padded to 960*16 (split-K x16, K%32==0)

__device__ __forceinline__ ushort_t f2bf(float f) {
  unsigned u = __float_as_uint(f);
  return (ushort_t)((u + 0x7fffu + ((u >> 16) & 1u)) >> 16);  // RNE
}
__device__ __forceinline__ float bf2f(ushort_t h) {
  return __uint_as_float(((unsigned)h) << 16);
}

// ---------------- block reduction helpers (256-thread blocks) ----------------
__device__ __forceinline__ float blockReduceSum256(float v, float* red) {
  #pragma unroll
  for (int o = 32; o; o >>= 1) v += __shfl_xor(v, o);
  int wid = threadIdx.x >> 6, lane = threadIdx.x & 63;
  if (lane == 0) red[wid] = v;
  __syncthreads();
  v = red[0] + red[1] + red[2] + red[3];
  __syncthreads();
  return v;
}
__device__ __forceinline__ float blockReduceMax256(float v, float* red) {
  #pragma unroll
  for (int o = 32; o; o >>= 1) v = fmaxf(v, __shfl_xor(v, o));
  int wid = threadIdx.x >> 6, lane = threadIdx.x & 63;
  if (lane == 0) red[wid] = v;
  __syncthreads();
  v = fmaxf(fmaxf(red[0], red[1]), fmaxf(red[2], red[3]));
  __syncthreads();
  return v;
}

// ============ 1-pass bf16 MFMA GEMM, 128x128 tile, conflict-free LDS ============
// C = A @ B^T (+bias). A: bf16. B: bf16 (BF16B) or fp32 (converted in staging).
// M = 512 exact. N ragged (guarded). K%32==0; kChunk%32==0 (split-K via z).
// ZFAST: grid is (z, mTile, nTile) so blocks sharing a K-slice land on one XCD.
// LDS layout: 16B unit (row,q) at unit-idx (row>>4)*64 + q*16 + (row&15)
//   -> frag read addr = base + 16*lane (conflict-free; SQ_LDS_BANK_CONFLICT==0);
//      stager thread t writes units {t, t+256} at bytes {16t, 16t+4096}.
template <bool BF16B, bool BIAS, bool CAUSAL, bool POUT, bool ZFAST>
__global__ __launch_bounds__(256, 2) void glds(
    const ushort_t* __restrict__ A, const void* __restrict__ Bv,
    const float* __restrict__ bias, float* __restrict__ C, ushort_t* __restrict__ Ch,
    int N, int K, int lda, int ldb, int ldc,
    int kChunk, long aZ, long bZ, long cZ)
{
  const int z  = ZFAST ? blockIdx.x : blockIdx.z;
  const int m0 = blockIdx.y * 128;
  const int n0 = (ZFAST ? blockIdx.z : blockIdx.x) * 128;
  if (CAUSAL && n0 > m0 + 127) return;   // tile fully above diagonal
  __shared__ ushort_t sA[4096], sB[4096];   // 512 units x 8 bf16 each
  const int tid = threadIdx.x;
  const int kBeg = kChunk ? z * kChunk : 0;
  const int kEnd = kChunk ? kBeg + kChunk : K;
  A += (size_t)z * aZ;
  const ushort_t* Bh = (const ushort_t*)Bv;
  const float*    Bf = (const float*)Bv;
  if (BF16B) Bh += (size_t)z * bZ; else Bf += (size_t)z * bZ;
  C += (size_t)z * cZ;
  if (POUT) Ch += (size_t)z * cZ;

  // staging map: thread t -> unit t (rows 0-63) and t+256 (rows 64-127)
  const int r0 = ((tid >> 6) << 4) | (tid & 15);   // unit t -> row
  const int q0 = (tid >> 4) & 3;                   // k-chunk within 32
  const int r1 = r0 + 64;
  const ushort_t* pA0 = A + (size_t)(m0 + r0) * lda + (q0 << 3);
  const ushort_t* pA1 = A + (size_t)(m0 + r1) * lda + (q0 << 3);
  const int gn0 = n0 + r0, gn1 = n0 + r1;
  const bool bok0 = gn0 < N, bok1 = gn1 < N;
  const ushort_t* pB0h = Bh + (size_t)gn0 * ldb + (q0 << 3);
  const ushort_t* pB1h = Bh + (size_t)gn1 * ldb + (q0 << 3);
  const float*    pB0f = Bf + (size_t)gn0 * ldb + (q0 << 3);
  const float*    pB1f = Bf + (size_t)gn1 * ldb + (q0 << 3);

  // waves 2x2, each 64x64
  const int lane = tid & 63;
  const int wrb = (tid >> 7) & 1;
  const int wcb = (tid >> 6) & 1;
  const int fr = lane & 15, fq = lane >> 4;

  f32x4 acc[4][4] = {};
  const short8 z8 = {0, 0, 0, 0, 0, 0, 0, 0};
  const float4 z4 = make_float4(0.f, 0.f, 0.f, 0.f);
  short8 ra0, ra1, rb0, rb1;
  float4 f00, f01, f10, f11;

  ra0 = *(const short8*)(pA0 + kBeg);
  ra1 = *(const short8*)(pA1 + kBeg);
  if (BF16B) {
    rb0 = bok0 ? *(const short8*)(pB0h + kBeg) : z8;
    rb1 = bok1 ? *(const short8*)(pB1h + kBeg) : z8;
  } else {
    f00 = bok0 ? *(const float4*)(pB0f + kBeg) : z4;
    f01 = bok0 ? *(const float4*)(pB0f + kBeg + 4) : z4;
    f10 = bok1 ? *(const float4*)(pB1f + kBeg) : z4;
    f11 = bok1 ? *(const float4*)(pB1f + kBeg + 4) : z4;
  }

  for (int k0 = kBeg; k0 < kEnd; k0 += 32) {
    __syncthreads();  // prior iter's fragment reads complete
    *(short8*)&sA[tid << 3] = ra0;
    *(short8*)&sA[(tid + 256) << 3] = ra1;
    if (BF16B) {
      *(short8*)&sB[tid << 3] = rb0;
      *(short8*)&sB[(tid + 256) << 3] = rb1;
    } else {
      short8 s0, s1;
      #pragma unroll
      for (int j = 0; j < 4; ++j) {
        s0[j] = (short)f2bf(f00[j]); s0[j + 4] = (short)f2bf(f01[j]);
        s1[j] = (short)f2bf(f10[j]); s1[j + 4] = (short)f2bf(f11[j]);
      }
      *(short8*)&sB[tid << 3] = s0;
      *(short8*)&sB[(tid + 256) << 3] = s1;
    }
    if (k0 + 32 < kEnd) {  // prefetch next k-step
      const int k = k0 + 32;
      ra0 = *(const short8*)(pA0 + k);
      ra1 = *(const short8*)(pA1 + k);
      if (BF16B) {
        rb0 = bok0 ? *(const short8*)(pB0h + k) : z8;
        rb1 = bok1 ? *(const short8*)(pB1h + k) : z8;
      } else {
        f00 = bok0 ? *(const float4*)(pB0f + k) : z4;
        f01 = bok0 ? *(const float4*)(pB0f + k + 4) : z4;
        f10 = bok1 ? *(const float4*)(pB1f + k) : z4;
        f11 = bok1 ? *(const float4*)(pB1f + k + 4) : z4;
      }
    }
    __syncthreads();  // writes visible

    short8 fa[4], fb[4];
    #pragma unroll
    for (int f = 0; f < 4; ++f)
      fa[f] = *(const short8*)&sA[((((wrb << 2) + f) << 9) | (lane << 3))];
    #pragma unroll
    for (int g = 0; g < 4; ++g)
      fb[g] = *(const short8*)&sB[((((wcb << 2) + g) << 9) | (lane << 3))];
    #pragma unroll
    for (int f = 0; f < 4; ++f)
      #pragma unroll
      for (int g = 0; g < 4; ++g)
        acc[f][g] = __builtin_amdgcn_mfma_f32_16x16x32_bf16(fa[f], fb[g], acc[f][g], 0, 0, 0);
  }

  // epilogue: C/D layout col=lane&15, row=(lane>>4)*4+reg
  #pragma unroll
  for (int f = 0; f < 4; ++f) {
    const int gm = m0 + (wrb << 6) + f * 16 + fq * 4;
    #pragma unroll
    for (int g = 0; g < 4; ++g) {
      const int gn = n0 + (wcb << 6) + g * 16 + fr;
      if (gn < N) {
        #pragma unroll
        for (int i = 0; i < 4; ++i) {
          float v = acc[f][g][i];
          if (BIAS) v += bias[gn];
          const size_t o = (size_t)(gm + i) * ldc + gn;
          if (POUT) Ch[o] = f2bf(v);
          else      C[o] = v;
        }
      }
    }
  }
}

// ---------------- split-K combine: outh = bf16(sum_z part[z] + bias (+relu)) ----------------
template <bool RELU>
__global__ __launch_bounds__(256) void combine(
    const float* __restrict__ part, const float* __restrict__ bias,
    ushort_t* __restrict__ outh, int nz, long zstride, int total4, int N4)
{
  const int i = blockIdx.x * 256 + threadIdx.x;
  if (i >= total4) return;
  float4 s = ((const float4*)bias)[i % N4];
  for (int z = 0; z < nz; ++z) {
    float4 p = ((const float4*)(part + (size_t)z * zstride))[i];
    s.x += p.x; s.y += p.y; s.z += p.z; s.w += p.w;
  }
  if (RELU) {
    s.x = fmaxf(s.x, 0.f); s.y = fmaxf(s.y, 0.f);
    s.z = fmaxf(s.z, 0.f); s.w = fmaxf(s.w, 0.f);
  }
  ((ushort4*)outh)[i] = make_ushort4(f2bf(s.x), f2bf(s.y), f2bf(s.z), f2bf(s.w));
}

// ---------------- fused split-K combine + residual + LayerNorm ----------------
__global__ __launch_bounds__(256) void ln_parts(
    const float* __restrict__ part, int nz, const float* __restrict__ bias,
    float* __restrict__ x, ushort_t* __restrict__ xh,
    const float* __restrict__ g, const float* __restrict__ b)
{
  const int t = blockIdx.x, tid = threadIdx.x;
  float4 y = ((const float4*)(x + (size_t)t * 1024))[tid];
  float4 s = ((const float4*)bias)[tid];
  for (int z = 0; z < nz; ++z) {
    float4 p = ((const float4*)(part + (size_t)z * 524288 + (size_t)t * 1024))[tid];
    s.x += p.x; s.y += p.y; s.z += p.z; s.w += p.w;
  }
  y.x += s.x; y.y += s.y; y.z += s.z; y.w += s.w;
  __shared__ float red[4];
  float sum = blockReduceSum256(y.x + y.y + y.z + y.w, red);
  const float m = sum * (1.f / 1024.f);
  float dx = y.x - m, dy = y.y - m, dz = y.z - m, dw = y.w - m;
  float q = blockReduceSum256(dx * dx + dy * dy + dz * dz + dw * dw, red);
  const float rs = rsqrtf(q * (1.f / 1024.f) + 1e-5f);
  float4 gg = ((const float4*)g)[tid], bb = ((const float4*)b)[tid];
  float4 o;
  o.x = dx * rs * gg.x + bb.x;
  o.y = dy * rs * gg.y + bb.y;
  o.z = dz * rs * gg.z + bb.z;
  o.w = dw * rs * gg.w + bb.w;
  ((float4*)(x + (size_t)t * 1024))[tid] = o;
  ((ushort4*)xh)[t * 256 + tid] = make_ushort4(f2bf(o.x), f2bf(o.y), f2bf(o.z), f2bf(o.w));
}

// ---------------- vectorized fp32 -> bf16 conversions (G13) ----------------
// aligned flat: rows are multiples of 4, no padding (W_vr, audio)
__global__ __launch_bounds__(256) void cvt_flat(
    const float* __restrict__ src, ushort_t* __restrict__ dst, int total4)
{
  const int i = blockIdx.x * 256 + threadIdx.x;
  if (i >= total4) return;
  float4 v = ((const float4*)src)[i];
  ((ushort4*)dst)[i] = make_ushort4(f2bf(v.x), f2bf(v.y), f2bf(v.z), f2bf(v.w));
}

// padded: src rows Csrc (odd ok, scalar loads), dst rows Cdst (mult of 4), zero tail
__global__ __launch_bounds__(256) void cvt_pad(
    const float* __restrict__ src, ushort_t* __restrict__ dst,
    int Csrc, int Cdst4, int total4)
{
  const int i = blockIdx.x * 256 + threadIdx.x;
  if (i >= total4) return;
  const int r = i / Cdst4;
  const int c = (i - r * Cdst4) << 2;
  const float* s = src + (size_t)r * Csrc + c;
  ushort4 o = make_ushort4(0, 0, 0, 0);
  if (c + 3 < Csrc) {
    o = make_ushort4(f2bf(s[0]), f2bf(s[1]), f2bf(s[2]), f2bf(s[3]));
  } else {
    if (c + 0 < Csrc) o.x = f2bf(s[0]);
    if (c + 1 < Csrc) o.y = f2bf(s[1]);
    if (c + 2 < Csrc) o.z = f2bf(s[2]);
    if (c + 3 < Csrc) o.w = f2bf(s[3]);
  }
  ((ushort4*)dst)[i] = o;
}

// vin input: bf16 of concat(0, vertice[:-1]) - tmpl, padded to KVIN
__global__ __launch_bounds__(256) void prep_vin_v(
    const float* __restrict__ vertice, const float* __restrict__ tmpl,
    ushort_t* __restrict__ dst, int total4)
{
  const int i = blockIdx.x * 256 + threadIdx.x;
  if (i >= total4) return;
  const int C4 = KVIN >> 2;
  const int t = i / C4;
  const int c = (i - t * C4) << 2;
  ushort4 o = make_ushort4(0, 0, 0, 0);
  if (t > 0) {
    const float* s = vertice + (size_t)(t - 1) * 15069 + c;
    if (c + 3 < 15069) {
      o = make_ushort4(f2bf(s[0] - tmpl[c]),     f2bf(s[1] - tmpl[c + 1]),
                       f2bf(s[2] - tmpl[c + 2]), f2bf(s[3] - tmpl[c + 3]));
    } else {
      if (c + 0 < 15069) o.x = f2bf(s[0] - tmpl[c]);
      if (c + 1 < 15069) o.y = f2bf(s[1] - tmpl[c + 1]);
      if (c + 2 < 15069) o.z = f2bf(s[2] - tmpl[c + 2]);
      if (c + 3 < 15069) o.w = f2bf(s[3] - tmpl[c + 3]);
    }
  }
  ((ushort4*)dst)[i] = o;
}

__global__ void prep_bias2(const float* __restrict__ one_hot, const float* __restrict__ W_obj,
                           const float* __restrict__ b_vm, float* __restrict__ bias2) {
  int d = blockIdx.x * 256 + threadIdx.x;
  if (d < 1024) {
    float s = 0.f;
    #pragma unroll
    for (int j = 0; j < 8; ++j) s += one_hot[j] * W_obj[d * 8 + j];
    bias2[d] = b_vm[d] + s;
  }
}

__global__ void prep_bias3(const float* __restrict__ b_vr, const float* __restrict__ tmpl,
                           float* __restrict__ bias3, int n) {
  int v = blockIdx.x * 256 + threadIdx.x;
  if (v < n) bias3[v] = b_vr[v] + tmpl[v];
}

// sum 16 vin split-K partials + bias2 + PE -> x (f32 + bf16)
__global__ __launch_bounds__(256) void reduce_pe(const float* __restrict__ part,
                                                 const float* __restrict__ bias2,
                                                 float* __restrict__ x,
                                                 ushort_t* __restrict__ xh) {
  const int t = blockIdx.x;
  const float PECOEF = -9.210340371976184f / 512.f;  // -ln(10000)/512
  const int p = t % 25;
  for (int d = threadIdx.x; d < 1024; d += 256) {
    float s = bias2[d];
    #pragma unroll
    for (int z = 0; z < 16; ++z) s += part[(size_t)z * 524288 + (size_t)t * 1024 + d];
    float arg = (float)p * expf((float)(d >> 1) * PECOEF);
    s += (d & 1) ? cosf(arg) : sinf(arg);
    const size_t idx = (size_t)t * 1024 + d;
    x[idx] = s;
    xh[idx] = f2bf(s);
  }
}

// V transpose from qkv split-K parts: vth[d][s] = bf16(sum_z part[z][s][2048+d] + bias)
__global__ __launch_bounds__(256) void vT_parts(const float* __restrict__ part,
                                                const float* __restrict__ bias,
                                                ushort_t* __restrict__ vth) {
  __shared__ float tile[32][33];
  const int s0 = blockIdx.x * 32, d0 = blockIdx.y * 32;
  const int tx = threadIdx.x & 31, ty = threadIdx.x >> 5;  // 32 x 8
  for (int r = ty; r < 32; r += 8) {
    float v = bias[2048 + d0 + tx];
    #pragma unroll
    for (int z = 0; z < 4; ++z)
      v += part[(size_t)z * 1572864 + (size_t)(s0 + r) * 3072 + 2048 + d0 + tx];
    tile[r][tx] = v;
  }
  __syncthreads();
  for (int r = ty; r < 32; r += 8)
    vth[(size_t)(d0 + r) * 512 + s0 + tx] = f2bf(tile[tx][r]);
}

// row softmax with ALIBI + causal; reads raw scores f32, writes attn bf16
__global__ __launch_bounds__(256) void softmax_alibi(const float* __restrict__ scores,
                                                     ushort_t* __restrict__ ah) {
  const int i = blockIdx.x, h = blockIdx.y;
  const size_t rb = ((size_t)h * 512 + i) * 512;
  const float* row = scores + rb;
  const int tid = threadIdx.x;
  const int len = i + 1;
  const float sl = exp2f(-2.f * (float)(h + 1));
  const int j0 = tid, j1 = tid + 256;
  float v0 = -INFINITY, v1 = -INFINITY;
  if (j0 < len) v0 = row[j0] * 0.0625f - sl * (float)((i - j0) / 25);
  if (j1 < len) v1 = row[j1] * 0.0625f - sl * (float)((i - j1) / 25);
  __shared__ float red[4];
  float m = blockReduceMax256(fmaxf(v0, v1), red);
  float e0 = (j0 < len) ? expf(v0 - m) : 0.f;
  float e1 = (j1 < len) ? expf(v1 - m) : 0.f;
  float s = blockReduceSum256(e0 + e1, red);
  float inv = 1.f / s;
  ah[rb + j0] = f2bf(e0 * inv);
  ah[rb + j1] = f2bf(e1 * inv);
}

// ---------------- host-side launch ----------------
extern "C" void kernel_launch(void* const* d_in, const int* in_sizes, int n_in,
                              void* d_out, int out_size, void* d_ws, size_t ws_size,
                              hipStream_t stream) {
  const float* audio   = (const float*)d_in[0];
  const float* vertice = (const float*)d_in[1];
  const float* tmpl    = (const float*)d_in[2];
  const float* one_hot = (const float*)d_in[3];
  const float* W_af    = (const float*)d_in[4];
  const float* b_af    = (const float*)d_in[5];
  const float* W_vm    = (const float*)d_in[6];
  const float* b_vm    = (const float*)d_in[7];
  const float* W_obj   = (const float*)d_in[8];
  const float* Wqkv_sa = (const float*)d_in[9];
  const float* bqkv_sa = (const float*)d_in[10];
  const float* Wo_sa   = (const float*)d_in[11];
  const float* bo_sa   = (const float*)d_in[12];
  const float* Wqkv_ca = (const float*)d_in[13];
  const float* bqkv_ca = (const float*)d_in[14];
  const float* Wo_ca   = (const float*)d_in[15];
  const float* bo_ca   = (const float*)d_in[16];
  const float* W1      = (const float*)d_in[17];
  const float* b1      = (const float*)d_in[18];
  const float* W2      = (const float*)d_in[19];
  const float* b2      = (const float*)d_in[20];
  const float* g1      = (const float*)d_in[21];
  const float* be1     = (const float*)d_in[22];
  const float* g2      = (const float*)d_in[23];
  const float* be2     = (const float*)d_in[24];
  const float* g3      = (const float*)d_in[25];
  const float* be3     = (const float*)d_in[26];
  const float* W_vr    = (const float*)d_in[27];
  const float* b_vr    = (const float*)d_in[28];
  float* out = (float*)d_out;

  // ---- workspace carve (floats), total ~100 MB ----
  float* base = (float*)d_ws;
  float* apF    = base;                  // 512*15360 us  = 3,932,160 fl
  float* wvmF   = apF + 3932160;         // 1024*15360 us = 7,864,320 fl (Wvm, then Wvr after vin)
  float* part   = wvmF + 7864320;        // 16*524288     = 8,388,608 fl
  float* x      = part + 8388608;        // 524,288
  float* xhF    = x + 524288;            // 262,144 (512*1024 us)
  float* audF   = xhF + 262144;          // 196,608 (512*768 us)
  float* hidF   = audF + 196608;         // 262,144
  float* qkvF   = hidF + 262144;         // 786,432 (512*3072 us)
  float* vtF    = qkvF + 786432;         // 262,144 (1024*512 us)
  float* scores = vtF + 262144;          // 1,048,576
  float* attF   = scores + 1048576;      // 524,288 (4*512*512 us)
  float* ctxF   = attF + 524288;         // 262,144
  float* cvF    = ctxF + 262144;         // 262,144
  float* h1F    = cvF + 262144;          // 524,288 (512*2048 us)
  float* bias2  = h1F + 524288;          // 1,024
  float* bias3  = bias2 + 1024;          // 15,072

  ushort_t* Aph  = (ushort_t*)apF;
  ushort_t* Wvmh = (ushort_t*)wvmF;
  ushort_t* Wvrh = (ushort_t*)wvmF;      // alias: Wvm dead after vin GEMM
  ushort_t* xh   = (ushort_t*)xhF;
  ushort_t* audh = (ushort_t*)audF;
  ushort_t* hidh = (ushort_t*)hidF;
  ushort_t* qkvh = (ushort_t*)qkvF;
  ushort_t* vth  = (ushort_t*)vtF;
  ushort_t* atth = (ushort_t*)attF;
  ushort_t* ctxh = (ushort_t*)ctxF;
  ushort_t* cvh  = (ushort_t*)cvF;
  ushort_t* h1h  = (ushort_t*)h1F;

  // ---- prep (all vectorized) ----
  prep_bias2<<<4, 256, 0, stream>>>(one_hot, W_obj, b_vm, bias2);
  prep_bias3<<<(15069 + 255) / 256, 256, 0, stream>>>(b_vr, tmpl, bias3, 15069);
  prep_vin_v<<<7680, 256, 0, stream>>>(vertice, tmpl, Aph, 512 * (KVIN / 4));
  cvt_pad<<<15360, 256, 0, stream>>>(W_vm, Wvmh, 15069, KVIN / 4, 1024 * (KVIN / 4));

  // ---- vin = Ap @ Wvm^T  (split-K x16, z-fastest grid for XCD/L2 locality) ----
  glds<true, false, false, false, true><<<dim3(16, 4, 8), 256, 0, stream>>>(
      Aph, Wvmh, nullptr, part, nullptr,
      1024, KVIN, KVIN, KVIN, 1024, 960, 0, 0, 524288);
  reduce_pe<<<512, 256, 0, stream>>>(part, bias2, x, xh);

  // Wvr bf16 (reuse wvm region; Wvm dead after vin GEMM above); rows aligned -> flat
  cvt_flat<<<15069, 256, 0, stream>>>(W_vr, Wvrh, 15069 * 256);

  // ---- hidden = audio @ W_af^T + b_af ----
  cvt_flat<<<384, 256, 0, stream>>>(audio, audh, 512 * 192);
  glds<false, false, false, false, false><<<dim3(8, 4, 6), 256, 0, stream>>>(
      audh, W_af, nullptr, part, nullptr,
      1024, 768, 768, 768, 1024, 128, 0, 0, 524288);
  combine<false><<<512, 256, 0, stream>>>(part, b_af, hidh, 6, 524288, 131072, 256);

  // ---- self attention ----
  glds<false, false, false, false, false><<<dim3(24, 4, 4), 256, 0, stream>>>(
      xh, Wqkv_sa, nullptr, part, nullptr,
      3072, 1024, 1024, 1024, 3072, 256, 0, 0, 1572864);
  combine<false><<<1536, 256, 0, stream>>>(part, bqkv_sa, qkvh, 4, 1572864, 393216, 768);
  vT_parts<<<dim3(16, 32), 256, 0, stream>>>(part, bqkv_sa, vth);
  // scores[h] = q_h @ k_h^T : z = head via kChunk=256 (causal tiles only)
  glds<true, false, true, false, false><<<dim3(4, 4, 4), 256, 0, stream>>>(
      qkvh, qkvh + 1024, nullptr, scores, nullptr,
      512, 1024, 3072, 3072, 512, 256, 0, 0, 262144);
  softmax_alibi<<<dim3(512, 4), 256, 0, stream>>>(scores, atth);
  // ctx[h] = attn_h @ vT_h^T, bf16 out directly
  glds<true, false, false, true, false><<<dim3(2, 4, 4), 256, 0, stream>>>(
      atth, vth, nullptr, nullptr, ctxh,
      256, 512, 512, 512, 1024, 0, 262144, 131072, 256);
  // out proj + LN
  glds<false, false, false, false, false><<<dim3(8, 4, 8), 256, 0, stream>>>(
      ctxh, Wo_sa, nullptr, part, nullptr,
      1024, 1024, 1024, 1024, 1024, 128, 0, 0, 524288);
  ln_parts<<<512, 256, 0, stream>>>(part, 8, bo_sa, x, xh, g1, be1);

  // ---- cross attention: bool mask == identity -> V then O projection ----
  glds<false, false, false, false, false><<<dim3(8, 4, 8), 256, 0, stream>>>(
      hidh, Wqkv_ca + (size_t)2048 * 1024, nullptr, part, nullptr,
      1024, 1024, 1024, 1024, 1024, 128, 0, 0, 524288);
  combine<false><<<512, 256, 0, stream>>>(part, bqkv_ca + 2048, cvh, 8, 524288, 131072, 256);
  glds<false, false, false, false, false><<<dim3(8, 4, 8), 256, 0, stream>>>(
      cvh, Wo_ca, nullptr, part, nullptr,
      1024, 1024, 1024, 1024, 1024, 128, 0, 0, 524288);
  ln_parts<<<512, 256, 0, stream>>>(part, 8, bo_ca, x, xh, g2, be2);

  // ---- feed forward ----
  glds<false, false, false, false, false><<<dim3(16, 4, 4), 256, 0, stream>>>(
      xh, W1, nullptr, part, nullptr,
      2048, 1024, 1024, 1024, 2048, 256, 0, 0, 1048576);
  combine<true><<<1024, 256, 0, stream>>>(part, b1, h1h, 4, 1048576, 262144, 512);
  glds<false, false, false, false, false><<<dim3(8, 4, 8), 256, 0, stream>>>(
      h1h, W2, nullptr, part, nullptr,
      1024, 2048, 2048, 2048, 1024, 256, 0, 0, 524288);
  ln_parts<<<512, 256, 0, stream>>>(part, 8, b2, x, xh, g3, be3);

  // ---- final projection: out = x @ W_vr^T + (b_vr + tmpl)  (pre-split bf16 B) ----
  glds<true, true, false, false, false><<<dim3(118, 4, 1), 256, 0, stream>>>(
      xh, Wvrh, bias3, out, nullptr,
      15069, 1024, 1024, 1024, 15069, 0, 0, 0, 0);
}